// Round 4
// baseline (829.165 us; speedup 1.0000x reference)
//
#include <hip/hip_runtime.h>

#define NN   100000
#define NE   1200000
#define MT   (NE + NN)      // edges + self loops
#define HH   4
#define HD   64             // H * OUT
#define NEG_SLOPE 0.2f
#define NB1  98             // ceil(NN/1024) scan blocks
#define BSH  7
#define BSZ  128            // cols per bucket
#define NBK  782            // ceil(NN/128)

// ---------------------------------------------------------------------------
// K1: content = x[:, :112] @ W  (tiled: 128 nodes x 64 outs / block,
//     4 nodes x 8 outs / thread), plus per-node scores.
//     si goes into ss[n*8 + h] (den lives at ss[n*8+4+h]); sj separate.
// ---------------------------------------------------------------------------
__global__ __launch_bounds__(256) void k_content(
    const float* __restrict__ x, const float* __restrict__ W,
    const float* __restrict__ att, const float* __restrict__ pos_att,
    float* __restrict__ content, float* __restrict__ ss, float* __restrict__ sj)
{
    __shared__ float Wl[112 * 64];     // 28672 B
    __shared__ float xsT[64 * 128];    // 32768 B, k-major, XOR-swizzled cols
    const int t = threadIdx.x;
    for (int i = t; i < 112 * 64; i += 256) Wl[i] = W[i];

    const int n0  = blockIdx.x * 128;
    const int oc  = (t & 7) * 8;       // output base (8 outs), within one head
    const int h   = oc >> 4;
    const int ng4 = (t >> 3) * 4;      // node base within block (0..124)

    float acc[4][8];
    #pragma unroll
    for (int j = 0; j < 4; ++j)
        #pragma unroll
        for (int o = 0; o < 8; ++o) acc[j][o] = 0.f;

    for (int ph = 0; ph < 2; ++ph) {
        __syncthreads();
        for (int idx = t; idx < 128 * 64; idx += 256) {
            const int nl = idx >> 6;
            const int kk = idx & 63;
            const int gn = n0 + nl;
            const float v = (gn < NN) ? x[gn * 128 + ph * 64 + kk] : 0.f;
            xsT[kk * 128 + (nl ^ ((kk & 31) << 2))] = v;
        }
        __syncthreads();
        const int klim = (ph == 0) ? 64 : 48;
        #pragma unroll 4
        for (int kk = 0; kk < klim; ++kk) {
            const int sw = (kk & 31) << 2;
            const float4 xv = *(const float4*)&xsT[kk * 128 + (ng4 ^ sw)];
            const int kg = ph * 64 + kk;
            const float4 w0 = *(const float4*)&Wl[kg * 64 + oc];
            const float4 w1 = *(const float4*)&Wl[kg * 64 + oc + 4];
            const float xa[4] = { xv.x, xv.y, xv.z, xv.w };
            #pragma unroll
            for (int j = 0; j < 4; ++j) {
                acc[j][0] = fmaf(xa[j], w0.x, acc[j][0]);
                acc[j][1] = fmaf(xa[j], w0.y, acc[j][1]);
                acc[j][2] = fmaf(xa[j], w0.z, acc[j][2]);
                acc[j][3] = fmaf(xa[j], w0.w, acc[j][3]);
                acc[j][4] = fmaf(xa[j], w1.x, acc[j][4]);
                acc[j][5] = fmaf(xa[j], w1.y, acc[j][5]);
                acc[j][6] = fmaf(xa[j], w1.z, acc[j][6]);
                acc[j][7] = fmaf(xa[j], w1.w, acc[j][7]);
            }
        }
    }

    const int dbase = oc & 15;
    float ati[8], atj[8], pti[8], ptj[8];
    #pragma unroll
    for (int j = 0; j < 8; ++j) {
        ati[j] = att[h * 32 + dbase + j];
        atj[j] = att[h * 32 + 16 + dbase + j];
        pti[j] = pos_att[h * 32 + dbase + j];
        ptj[j] = pos_att[h * 32 + 16 + dbase + j];
    }
    #pragma unroll
    for (int j = 0; j < 4; ++j) {
        const int gn = n0 + ng4 + j;
        float s1 = 0.f, s2 = 0.f;
        #pragma unroll
        for (int o = 0; o < 8; ++o) {
            s1 = fmaf(acc[j][o], ati[o], s1);
            s2 = fmaf(acc[j][o], atj[o], s2);
        }
        #pragma unroll
        for (int pp = 0; pp < 8; ++pp) {
            const int row = 48 + dbase + pp;
            const float pv = xsT[row * 128 + ((ng4 + j) ^ ((row & 31) << 2))];
            s1 = fmaf(pv, pti[pp], s1);
            s2 = fmaf(pv, ptj[pp], s2);
        }
        s1 += __shfl_xor(s1, 1);
        s2 += __shfl_xor(s2, 1);
        if (gn < NN) {
            if ((t & 1) == 0) ss[gn * 8 + h] = s1;
            else              sj[gn * 4 + h] = s2;
            float4 lo = { acc[j][0], acc[j][1], acc[j][2], acc[j][3] };
            float4 hi = { acc[j][4], acc[j][5], acc[j][6], acc[j][7] };
            *(float4*)&content[gn * 64 + oc]     = lo;
            *(float4*)&content[gn * 64 + oc + 4] = hi;
        }
    }
}

// ---------------------------------------------------------------------------
// K2: histogram of destination (col) counts
// ---------------------------------------------------------------------------
__global__ __launch_bounds__(256) void k_hist(
    const int* __restrict__ ei, int* __restrict__ cnt)
{
    const int e = blockIdx.x * 256 + threadIdx.x;
    if (e >= MT) return;
    const int c = (e < NE) ? ei[NE + e] : (e - NE);
    atomicAdd(cnt + c, 1);
}

// K3a: per-block exclusive scan of cnt (1024 elems/block), block sums out
__global__ __launch_bounds__(256) void k_scan1(
    const int* __restrict__ cnt, int* __restrict__ loc, int* __restrict__ bsum)
{
    const int b = blockIdx.x, t = threadIdx.x;
    const int base = b * 1024 + t * 4;
    int v[4], tsum = 0;
    #pragma unroll
    for (int j = 0; j < 4; ++j) {
        v[j] = (base + j < NN) ? cnt[base + j] : 0;
        tsum += v[j];
    }
    const int lane = t & 63, w = t >> 6;
    int sc = tsum;
    #pragma unroll
    for (int d = 1; d < 64; d <<= 1) {
        const int u = __shfl_up(sc, d);
        if (lane >= d) sc += u;
    }
    __shared__ int wsum[4];
    if (lane == 63) wsum[w] = sc;
    __syncthreads();
    int wbase = 0;
    for (int k = 0; k < w; ++k) wbase += wsum[k];
    int run = wbase + sc - tsum;
    #pragma unroll
    for (int j = 0; j < 4; ++j) {
        if (base + j < NN) loc[base + j] = run;
        run += v[j];
    }
    if (t == 255) bsum[b] = wbase + sc;
}

// K3b: serial exclusive scan of the 98 block sums
__global__ void k_scan2(int* __restrict__ bsum)
{
    if (threadIdx.x == 0 && blockIdx.x == 0) {
        int run = 0;
        for (int i = 0; i < NB1; ++i) { const int v = bsum[i]; bsum[i] = run; run += v; }
    }
}

// K3c: add block bases; emit bucket base cursors
__global__ __launch_bounds__(256) void k_scan3(
    int* __restrict__ offsets, const int* __restrict__ bsum, int* __restrict__ bwoff)
{
    const int i = blockIdx.x * 256 + threadIdx.x;
    if (i == 0) offsets[NN] = MT;
    if (i >= NN) return;
    const int off = offsets[i] + bsum[i >> 10];
    offsets[i] = off;
    if ((i & (BSZ - 1)) == 0) bwoff[i >> BSH] = off;
}

// ---------------------------------------------------------------------------
// K4 Phase A: per edge: ea = exp(lrelu(si[r]+sj[c])); den atomics into ss;
//             append 4B packed record {r | lcol<<17} to col-bucket.
// ---------------------------------------------------------------------------
__global__ __launch_bounds__(256) void k_bscatter(
    const int* __restrict__ ei, float* __restrict__ ss,
    const float* __restrict__ sj, int* __restrict__ bwoff,
    unsigned int* __restrict__ recs)
{
    const int e = blockIdx.x * 256 + threadIdx.x;
    if (e >= MT) return;
    int r, c;
    if (e < NE) { r = ei[e]; c = ei[NE + e]; } else { r = e - NE; c = r; }
    const float4 s1 = *(const float4*)(ss + (size_t)r * 8);
    const float4 s2 = *(const float4*)(sj + (size_t)c * 4);
    const float a[4] = { s1.x + s2.x, s1.y + s2.y, s1.z + s2.z, s1.w + s2.w };
    #pragma unroll
    for (int hh = 0; hh < 4; ++hh) {
        float v = a[hh];
        v = v > 0.f ? v : NEG_SLOPE * v;
        atomicAdd(ss + (size_t)r * 8 + 4 + hh, expf(v));
    }
    const int pos = atomicAdd(bwoff + (c >> BSH), 1);
    recs[pos] = (unsigned)r | ((unsigned)(c & (BSZ - 1)) << 17);
}

// ---------------------------------------------------------------------------
// K5 Phase B: one block per bucket. Finish sort with LDS per-col cursors,
//             recompute ea, alpha = ea/den (one 32B random L2 load for si+den),
//             write sorted_r / sorted_al (L2-local), gram accumulation.
// ---------------------------------------------------------------------------
__global__ __launch_bounds__(256) void k_bsort(
    const int* __restrict__ offsets, const unsigned int* __restrict__ recs,
    const float* __restrict__ ss, const float* __restrict__ sj,
    int* __restrict__ sorted_r, float* __restrict__ sorted_al,
    double* __restrict__ pairs)
{
    __shared__ int cur[BSZ];
    __shared__ float sjl[BSZ * 4];
    const int b = blockIdx.x, t = threadIdx.x;
    const int cbase = b << BSH;
    const int ncols = min(BSZ, NN - cbase);
    if (t < BSZ) cur[t] = (t < ncols) ? offsets[cbase + t] : 0;
    for (int i = t; i < ncols * 4; i += 256) sjl[i] = sj[(size_t)cbase * 4 + i];
    __syncthreads();
    const int s0 = offsets[cbase];
    const int s1 = offsets[min(cbase + BSZ, NN)];
    float a0=0,a1=0,a2=0,a3=0,a4=0,a5=0,a6=0,a7=0,a8=0,a9=0;
    for (int i = s0 + t; i < s1; i += 256) {
        const unsigned rec = recs[i];
        const int r  = (int)(rec & 0x1FFFFu);
        const int lc = (int)(rec >> 17);
        const float4 sv = *(const float4*)(ss + (size_t)r * 8);
        const float4 dd = *(const float4*)(ss + (size_t)r * 8 + 4);
        const float4 jv = *(const float4*)(sjl + lc * 4);
        float v0 = sv.x + jv.x, v1 = sv.y + jv.y, v2 = sv.z + jv.z, v3 = sv.w + jv.w;
        v0 = v0 > 0.f ? v0 : NEG_SLOPE * v0;
        v1 = v1 > 0.f ? v1 : NEG_SLOPE * v1;
        v2 = v2 > 0.f ? v2 : NEG_SLOPE * v2;
        v3 = v3 > 0.f ? v3 : NEG_SLOPE * v3;
        const float al0 = expf(v0) / (dd.x + 1e-10f);
        const float al1 = expf(v1) / (dd.y + 1e-10f);
        const float al2 = expf(v2) / (dd.z + 1e-10f);
        const float al3 = expf(v3) / (dd.w + 1e-10f);
        const int pos = atomicAdd(&cur[lc], 1);
        sorted_r[pos] = r;
        const float4 al4 = { al0, al1, al2, al3 };
        *(float4*)(sorted_al + (size_t)pos * 4) = al4;
        a0=fmaf(al0,al0,a0); a1=fmaf(al0,al1,a1); a2=fmaf(al0,al2,a2); a3=fmaf(al0,al3,a3);
        a4=fmaf(al1,al1,a4); a5=fmaf(al1,al2,a5); a6=fmaf(al1,al3,a6);
        a7=fmaf(al2,al2,a7); a8=fmaf(al2,al3,a8); a9=fmaf(al3,al3,a9);
    }
    #pragma unroll
    for (int m = 32; m >= 1; m >>= 1) {
        a0 += __shfl_xor(a0, m); a1 += __shfl_xor(a1, m);
        a2 += __shfl_xor(a2, m); a3 += __shfl_xor(a3, m);
        a4 += __shfl_xor(a4, m); a5 += __shfl_xor(a5, m);
        a6 += __shfl_xor(a6, m); a7 += __shfl_xor(a7, m);
        a8 += __shfl_xor(a8, m); a9 += __shfl_xor(a9, m);
    }
    __shared__ double red[4][10];
    const int lane = t & 63, wid = t >> 6;
    if (lane == 0) {
        red[wid][0]=a0; red[wid][1]=a1; red[wid][2]=a2; red[wid][3]=a3; red[wid][4]=a4;
        red[wid][5]=a5; red[wid][6]=a6; red[wid][7]=a7; red[wid][8]=a8; red[wid][9]=a9;
    }
    __syncthreads();
    if (t < 10) {
        const double s = red[0][t] + red[1][t] + red[2][t] + red[3][t];
        atomicAdd(pairs + t, s);
    }
}

// ---------------------------------------------------------------------------
// K6: one wave per destination node; coalesced r-preload + shfl broadcast,
//     8 independent content-row loads in flight.
// ---------------------------------------------------------------------------
__global__ __launch_bounds__(256) void k_gather(
    const int* __restrict__ offsets, const int* __restrict__ sorted_r,
    const float* __restrict__ sorted_al, const float* __restrict__ content,
    const float* __restrict__ bias, float* __restrict__ out)
{
    const int lane = threadIdx.x & 63;
    const int wid  = threadIdx.x >> 6;
    const int n    = blockIdx.x * 4 + wid;
    const int h    = lane >> 4;
    const int s0 = offsets[n], s1 = offsets[n + 1];
    float acc = 0.f;
    for (int base = s0; base < s1; base += 64) {
        const int cd = min(64, s1 - base);
        const int rl = (lane < cd) ? sorted_r[base + lane] : 0;
        int j = 0;
        for (; j + 7 < cd; j += 8) {
            int   rr[8];
            float al[8], cv[8];
            #pragma unroll
            for (int k = 0; k < 8; ++k) rr[k] = __shfl(rl, j + k);
            #pragma unroll
            for (int k = 0; k < 8; ++k) al[k] = sorted_al[(size_t)(base + j + k) * 4 + h];
            #pragma unroll
            for (int k = 0; k < 8; ++k) cv[k] = content[(size_t)rr[k] * 64 + lane];
            #pragma unroll
            for (int k = 0; k < 8; ++k) acc = fmaf(cv[k], al[k], acc);
        }
        for (; j < cd; ++j) {
            const int r0 = __shfl(rl, j);
            const float al0 = sorted_al[(size_t)(base + j) * 4 + h];
            acc = fmaf(content[(size_t)r0 * 64 + lane], al0, acc);
        }
    }
    out[(size_t)n * 64 + lane] = acc + bias[lane];
}

// K7: finalize diversity loss
__global__ void k_loss(const double* __restrict__ ps, float* __restrict__ out)
{
    if (threadIdx.x == 0 && blockIdx.x == 0) {
        const double s00=ps[0], s01=ps[1], s02=ps[2], s03=ps[3], s11=ps[4];
        const double s12=ps[5], s13=ps[6], s22=ps[7], s23=ps[8], s33=ps[9];
        const double n0 = fmax(sqrt(s00), 1e-12);
        const double n1 = fmax(sqrt(s11), 1e-12);
        const double n2 = fmax(sqrt(s22), 1e-12);
        const double n3 = fmax(sqrt(s33), 1e-12);
        double loss = 2.0 * ( s01/(n0*n1) + s02/(n0*n2) + s03/(n0*n3)
                            + s12/(n1*n2) + s13/(n1*n3) + s23/(n2*n3) );
        loss = loss / 16.0 * 0.1;
        out[NN * HD] = (float)loss;
    }
}

extern "C" void kernel_launch(void* const* d_in, const int* in_sizes, int n_in,
                              void* d_out, int out_size, void* d_ws, size_t ws_size,
                              hipStream_t stream)
{
    const float* x       = (const float*)d_in[0];
    const int*   ei      = (const int*)d_in[1];
    const float* W       = (const float*)d_in[2];
    const float* att     = (const float*)d_in[3];
    const float* pos_att = (const float*)d_in[4];
    const float* bias    = (const float*)d_in[5];
    float* out = (float*)d_out;

    // workspace layout (16B aligned). memset region = pairs|ss|cnt contiguous.
    char* p = (char*)d_ws;
    double* pairs    = (double*)p;        p += 128;
    float*  ss       = (float*)p;         p += (size_t)NN * 8 * 4;     // si(4)+den(4): 3.2 MB
    int*    cnt      = (int*)p;           p += (size_t)NN * 4;         // 400 KB
    int*    offsets  = (int*)p;           p += (size_t)(NN + 4) * 4;   // 400 KB
    int*    bsum     = (int*)p;           p += 512;
    int*    bwoff    = (int*)p;           p += 4096;                   // NBK cursors
    unsigned int* recs = (unsigned int*)p; p += (size_t)MT * 4;        // 5.2 MB
    int*    sorted_r = (int*)p;           p += (size_t)MT * 4;         // 5.2 MB
    float*  sj       = (float*)p;         p += (size_t)NN * 4 * 4;     // 1.6 MB
    float*  content  = (float*)p;         p += (size_t)NN * 64 * 4;    // 25.6 MB
    float*  sorted_al= (float*)p;         p += (size_t)MT * 16;        // 20.8 MB

    hipMemsetAsync(pairs, 0, 128 + (size_t)NN * 32 + (size_t)NN * 4, stream);

    k_content <<<(NN + 127) / 128, 256, 0, stream>>>(x, W, att, pos_att, content, ss, sj);
    k_hist    <<<(MT + 255) / 256, 256, 0, stream>>>(ei, cnt);
    k_scan1   <<<NB1, 256, 0, stream>>>(cnt, offsets, bsum);
    k_scan2   <<<1, 64, 0, stream>>>(bsum);
    k_scan3   <<<(NN + 255) / 256, 256, 0, stream>>>(offsets, bsum, bwoff);
    k_bscatter<<<(MT + 255) / 256, 256, 0, stream>>>(ei, ss, sj, bwoff, recs);
    k_bsort   <<<NBK, 256, 0, stream>>>(offsets, recs, ss, sj, sorted_r, sorted_al, pairs);
    k_gather  <<<NN / 4, 256, 0, stream>>>(offsets, sorted_r, sorted_al, content, bias, out);
    k_loss    <<<1, 64, 0, stream>>>(pairs, out);
}

// Round 5
// 566.756 us; speedup vs baseline: 1.4630x; 1.4630x over previous
//
#include <hip/hip_runtime.h>

#define NN   100000
#define NE   1200000
#define MT   (NE + NN)      // edges + self loops
#define HH   4
#define HD   64             // H * OUT
#define NEG_SLOPE 0.2f
#define NB1  98             // ceil(NN/1024) scan blocks
#define NGB  25000          // gather blocks (NN/4)

static __device__ __forceinline__ unsigned short f2bf(float f) {
    unsigned int b = __float_as_uint(f);
    b += 0x7FFFu + ((b >> 16) & 1u);
    return (unsigned short)(b >> 16);
}

// ---------------------------------------------------------------------------
// K1: content = x[:, :112] @ W (128 nodes x 64 outs / block), bf16 store,
//     plus per-node scores: si -> ss[n*8+h] (den slots ss[n*8+4+h]), sj.
// ---------------------------------------------------------------------------
__global__ __launch_bounds__(256) void k_content(
    const float* __restrict__ x, const float* __restrict__ W,
    const float* __restrict__ att, const float* __restrict__ pos_att,
    unsigned short* __restrict__ contentb, float* __restrict__ ss,
    float* __restrict__ sj)
{
    __shared__ float Wl[112 * 64];
    __shared__ float xsT[64 * 128];
    const int t = threadIdx.x;
    for (int i = t; i < 112 * 64; i += 256) Wl[i] = W[i];

    const int n0  = blockIdx.x * 128;
    const int oc  = (t & 7) * 8;
    const int h   = oc >> 4;
    const int ng4 = (t >> 3) * 4;

    float acc[4][8];
    #pragma unroll
    for (int j = 0; j < 4; ++j)
        #pragma unroll
        for (int o = 0; o < 8; ++o) acc[j][o] = 0.f;

    for (int ph = 0; ph < 2; ++ph) {
        __syncthreads();
        for (int idx = t; idx < 128 * 64; idx += 256) {
            const int nl = idx >> 6;
            const int kk = idx & 63;
            const int gn = n0 + nl;
            const float v = (gn < NN) ? x[gn * 128 + ph * 64 + kk] : 0.f;
            xsT[kk * 128 + (nl ^ ((kk & 31) << 2))] = v;
        }
        __syncthreads();
        const int klim = (ph == 0) ? 64 : 48;
        #pragma unroll 4
        for (int kk = 0; kk < klim; ++kk) {
            const int sw = (kk & 31) << 2;
            const float4 xv = *(const float4*)&xsT[kk * 128 + (ng4 ^ sw)];
            const int kg = ph * 64 + kk;
            const float4 w0 = *(const float4*)&Wl[kg * 64 + oc];
            const float4 w1 = *(const float4*)&Wl[kg * 64 + oc + 4];
            const float xa[4] = { xv.x, xv.y, xv.z, xv.w };
            #pragma unroll
            for (int j = 0; j < 4; ++j) {
                acc[j][0] = fmaf(xa[j], w0.x, acc[j][0]);
                acc[j][1] = fmaf(xa[j], w0.y, acc[j][1]);
                acc[j][2] = fmaf(xa[j], w0.z, acc[j][2]);
                acc[j][3] = fmaf(xa[j], w0.w, acc[j][3]);
                acc[j][4] = fmaf(xa[j], w1.x, acc[j][4]);
                acc[j][5] = fmaf(xa[j], w1.y, acc[j][5]);
                acc[j][6] = fmaf(xa[j], w1.z, acc[j][6]);
                acc[j][7] = fmaf(xa[j], w1.w, acc[j][7]);
            }
        }
    }

    const int dbase = oc & 15;
    float ati[8], atj[8], pti[8], ptj[8];
    #pragma unroll
    for (int j = 0; j < 8; ++j) {
        ati[j] = att[h * 32 + dbase + j];
        atj[j] = att[h * 32 + 16 + dbase + j];
        pti[j] = pos_att[h * 32 + dbase + j];
        ptj[j] = pos_att[h * 32 + 16 + dbase + j];
    }
    #pragma unroll
    for (int j = 0; j < 4; ++j) {
        const int gn = n0 + ng4 + j;
        float s1 = 0.f, s2 = 0.f;
        #pragma unroll
        for (int o = 0; o < 8; ++o) {
            s1 = fmaf(acc[j][o], ati[o], s1);
            s2 = fmaf(acc[j][o], atj[o], s2);
        }
        #pragma unroll
        for (int pp = 0; pp < 8; ++pp) {
            const int row = 48 + dbase + pp;
            const float pv = xsT[row * 128 + ((ng4 + j) ^ ((row & 31) << 2))];
            s1 = fmaf(pv, pti[pp], s1);
            s2 = fmaf(pv, ptj[pp], s2);
        }
        s1 += __shfl_xor(s1, 1);
        s2 += __shfl_xor(s2, 1);
        if (gn < NN) {
            if ((t & 1) == 0) ss[gn * 8 + h] = s1;
            else              sj[gn * 4 + h] = s2;
            uint4 pk;
            pk.x = (unsigned)f2bf(acc[j][0]) | ((unsigned)f2bf(acc[j][1]) << 16);
            pk.y = (unsigned)f2bf(acc[j][2]) | ((unsigned)f2bf(acc[j][3]) << 16);
            pk.z = (unsigned)f2bf(acc[j][4]) | ((unsigned)f2bf(acc[j][5]) << 16);
            pk.w = (unsigned)f2bf(acc[j][6]) | ((unsigned)f2bf(acc[j][7]) << 16);
            *(uint4*)&contentb[(size_t)gn * 64 + oc] = pk;
        }
    }
}

// ---------------------------------------------------------------------------
// K2: histogram of destination (col) counts
// ---------------------------------------------------------------------------
__global__ __launch_bounds__(256) void k_hist(
    const int* __restrict__ ei, int* __restrict__ cnt)
{
    const int e = blockIdx.x * 256 + threadIdx.x;
    if (e >= MT) return;
    const int c = (e < NE) ? ei[NE + e] : (e - NE);
    atomicAdd(cnt + c, 1);
}

// K3a: per-block exclusive scan of cnt (1024 elems/block)
__global__ __launch_bounds__(256) void k_scan1(
    const int* __restrict__ cnt, int* __restrict__ loc, int* __restrict__ bsum)
{
    const int b = blockIdx.x, t = threadIdx.x;
    const int base = b * 1024 + t * 4;
    int v[4], tsum = 0;
    #pragma unroll
    for (int j = 0; j < 4; ++j) {
        v[j] = (base + j < NN) ? cnt[base + j] : 0;
        tsum += v[j];
    }
    const int lane = t & 63, w = t >> 6;
    int sc = tsum;
    #pragma unroll
    for (int d = 1; d < 64; d <<= 1) {
        const int u = __shfl_up(sc, d);
        if (lane >= d) sc += u;
    }
    __shared__ int wsum[4];
    if (lane == 63) wsum[w] = sc;
    __syncthreads();
    int wbase = 0;
    for (int k = 0; k < w; ++k) wbase += wsum[k];
    int run = wbase + sc - tsum;
    #pragma unroll
    for (int j = 0; j < 4; ++j) {
        if (base + j < NN) loc[base + j] = run;
        run += v[j];
    }
    if (t == 255) bsum[b] = wbase + sc;
}

// K3b: serial exclusive scan of the 98 block sums
__global__ void k_scan2(int* __restrict__ bsum)
{
    if (threadIdx.x == 0 && blockIdx.x == 0) {
        int run = 0;
        for (int i = 0; i < NB1; ++i) { const int v = bsum[i]; bsum[i] = run; run += v; }
    }
}

// K3c: add block bases; produce offsets and working cursor copy woff
__global__ __launch_bounds__(256) void k_scan3(
    int* __restrict__ offsets, const int* __restrict__ bsum, int* __restrict__ woff)
{
    const int i = blockIdx.x * 256 + threadIdx.x;
    if (i == 0) offsets[NN] = MT;
    if (i >= NN) return;
    const int off = offsets[i] + bsum[i >> 10];
    offsets[i] = off;
    woff[i] = off;
}

// ---------------------------------------------------------------------------
// K4: per edge: den atomics (ss[r] line, warm) + 4B counting-sort scatter.
//     NO payload scatter — alpha recomputed in gather.
// ---------------------------------------------------------------------------
__global__ __launch_bounds__(256) void k_edge(
    const int* __restrict__ ei, float* __restrict__ ss,
    const float* __restrict__ sj, int* __restrict__ woff,
    int* __restrict__ sorted_r)
{
    const int e = blockIdx.x * 256 + threadIdx.x;
    if (e >= MT) return;
    int r, c;
    if (e < NE) { r = ei[e]; c = ei[NE + e]; } else { r = e - NE; c = r; }
    const float4 s1 = *(const float4*)(ss + (size_t)r * 8);
    const float4 s2 = *(const float4*)(sj + (size_t)c * 4);
    const float a[4] = { s1.x + s2.x, s1.y + s2.y, s1.z + s2.z, s1.w + s2.w };
    #pragma unroll
    for (int hh = 0; hh < 4; ++hh) {
        float v = a[hh];
        v = v > 0.f ? v : NEG_SLOPE * v;
        atomicAdd(ss + (size_t)r * 8 + 4 + hh, __expf(v));
    }
    const int pos = atomicAdd(woff + c, 1);
    sorted_r[pos] = r;
}

// ---------------------------------------------------------------------------
// K5: one wave per destination node. Coalesced sorted_r preload + shfl
//     broadcast; per record: broadcast-load {si,den} line, recompute alpha,
//     bf16 content fma; gram via 4 shfls; per-block f32 partials (no atomics).
// ---------------------------------------------------------------------------
__global__ __launch_bounds__(256) void k_gather(
    const int* __restrict__ offsets, const int* __restrict__ sorted_r,
    const float* __restrict__ ss, const float* __restrict__ sj,
    const unsigned short* __restrict__ contentb, const float* __restrict__ bias,
    float* __restrict__ out, float* __restrict__ gpart)
{
    const int lane = threadIdx.x & 63;
    const int wid  = threadIdx.x >> 6;
    const int n    = blockIdx.x * 4 + wid;
    const int h    = lane >> 4;
    const int s0 = offsets[n], s1 = offsets[n + 1];
    const float sjh = sj[(size_t)n * 4 + h];
    float acc = 0.f;
    float a0=0,a1=0,a2=0,a3=0,a4=0,a5=0,a6=0,a7=0,a8=0,a9=0;

    for (int base = s0; base < s1; base += 64) {
        const int cd = min(64, s1 - base);
        const int rl = (lane < cd) ? sorted_r[base + lane] : 0;
        for (int j = 0; j < cd; ++j) {
            const int rk = __shfl(rl, j);
            const float sih  = ss[(size_t)rk * 8 + h];
            const float denh = ss[(size_t)rk * 8 + 4 + h];
            float v = sih + sjh;
            v = v > 0.f ? v : NEG_SLOPE * v;
            const float al = __expf(v) / (denh + 1e-10f);
            const float cv = __uint_as_float((unsigned)contentb[(size_t)rk * 64 + lane] << 16);
            acc = fmaf(cv, al, acc);
            const float b0 = __shfl(al, 0);
            const float b1 = __shfl(al, 16);
            const float b2 = __shfl(al, 32);
            const float b3 = __shfl(al, 48);
            a0=fmaf(b0,b0,a0); a1=fmaf(b0,b1,a1); a2=fmaf(b0,b2,a2); a3=fmaf(b0,b3,a3);
            a4=fmaf(b1,b1,a4); a5=fmaf(b1,b2,a5); a6=fmaf(b1,b3,a6);
            a7=fmaf(b2,b2,a7); a8=fmaf(b2,b3,a8); a9=fmaf(b3,b3,a9);
        }
    }
    out[(size_t)n * 64 + lane] = acc + bias[lane];

    // per-block gram partials: lane0 of each wave holds the full wave sum
    __shared__ float red[4][10];
    if (lane == 0) {
        red[wid][0]=a0; red[wid][1]=a1; red[wid][2]=a2; red[wid][3]=a3; red[wid][4]=a4;
        red[wid][5]=a5; red[wid][6]=a6; red[wid][7]=a7; red[wid][8]=a8; red[wid][9]=a9;
    }
    __syncthreads();
    if (threadIdx.x < 10) {
        gpart[(size_t)blockIdx.x * 10 + threadIdx.x] =
            red[0][threadIdx.x] + red[1][threadIdx.x] +
            red[2][threadIdx.x] + red[3][threadIdx.x];
    }
}

// K6: reduce per-block gram partials -> pairs (f64)
__global__ __launch_bounds__(256) void k_gred(
    const float* __restrict__ gpart, double* __restrict__ pairs)
{
    const int row = blockIdx.x * 256 + threadIdx.x;
    float v[10];
    #pragma unroll
    for (int i = 0; i < 10; ++i)
        v[i] = (row < NGB) ? gpart[(size_t)row * 10 + i] : 0.f;
    #pragma unroll
    for (int m = 32; m >= 1; m >>= 1)
        #pragma unroll
        for (int i = 0; i < 10; ++i) v[i] += __shfl_xor(v[i], m);
    __shared__ float red[4][10];
    const int lane = threadIdx.x & 63, wid = threadIdx.x >> 6;
    if (lane == 0)
        #pragma unroll
        for (int i = 0; i < 10; ++i) red[wid][i] = v[i];
    __syncthreads();
    if (threadIdx.x < 10) {
        const double s = (double)red[0][threadIdx.x] + red[1][threadIdx.x]
                       + red[2][threadIdx.x] + red[3][threadIdx.x];
        atomicAdd(pairs + threadIdx.x, s);
    }
}

// K7: finalize diversity loss
__global__ void k_loss(const double* __restrict__ ps, float* __restrict__ out)
{
    if (threadIdx.x == 0 && blockIdx.x == 0) {
        const double s00=ps[0], s01=ps[1], s02=ps[2], s03=ps[3], s11=ps[4];
        const double s12=ps[5], s13=ps[6], s22=ps[7], s23=ps[8], s33=ps[9];
        const double n0 = fmax(sqrt(s00), 1e-12);
        const double n1 = fmax(sqrt(s11), 1e-12);
        const double n2 = fmax(sqrt(s22), 1e-12);
        const double n3 = fmax(sqrt(s33), 1e-12);
        double loss = 2.0 * ( s01/(n0*n1) + s02/(n0*n2) + s03/(n0*n3)
                            + s12/(n1*n2) + s13/(n1*n3) + s23/(n2*n3) );
        loss = loss / 16.0 * 0.1;
        out[NN * HD] = (float)loss;
    }
}

extern "C" void kernel_launch(void* const* d_in, const int* in_sizes, int n_in,
                              void* d_out, int out_size, void* d_ws, size_t ws_size,
                              hipStream_t stream)
{
    const float* x       = (const float*)d_in[0];
    const int*   ei      = (const int*)d_in[1];
    const float* W       = (const float*)d_in[2];
    const float* att     = (const float*)d_in[3];
    const float* pos_att = (const float*)d_in[4];
    const float* bias    = (const float*)d_in[5];
    float* out = (float*)d_out;

    // workspace layout (16B aligned). memset region = pairs|ss|cnt contiguous.
    char* p = (char*)d_ws;
    double* pairs    = (double*)p;         p += 128;
    float*  ss       = (float*)p;          p += (size_t)NN * 8 * 4;     // si4+den4: 3.2 MB
    int*    cnt      = (int*)p;            p += (size_t)NN * 4;         // 400 KB (reused as woff)
    int*    offsets  = (int*)p;            p += (size_t)(NN + 4) * 4;   // 400 KB
    int*    bsum     = (int*)p;            p += 512;
    int*    sorted_r = (int*)p;            p += (size_t)MT * 4;         // 5.2 MB
    float*  sj       = (float*)p;          p += (size_t)NN * 4 * 4;     // 1.6 MB
    float*  gpart    = (float*)p;          p += (size_t)NGB * 10 * 4;   // 1.0 MB
    unsigned short* contentb = (unsigned short*)p; p += (size_t)NN * 64 * 2; // 12.8 MB

    hipMemsetAsync(pairs, 0, 128 + (size_t)NN * 32 + (size_t)NN * 4, stream);

    k_content<<<(NN + 127) / 128, 256, 0, stream>>>(x, W, att, pos_att, contentb, ss, sj);
    k_hist   <<<(MT + 255) / 256, 256, 0, stream>>>(ei, cnt);
    k_scan1  <<<NB1, 256, 0, stream>>>(cnt, offsets, bsum);
    k_scan2  <<<1, 64, 0, stream>>>(bsum);
    k_scan3  <<<(NN + 255) / 256, 256, 0, stream>>>(offsets, bsum, cnt);
    k_edge   <<<(MT + 255) / 256, 256, 0, stream>>>(ei, ss, sj, cnt, sorted_r);
    k_gather <<<NGB, 256, 0, stream>>>(offsets, sorted_r, ss, sj, contentb, bias, out, gpart);
    k_gred   <<<(NGB + 255) / 256, 256, 0, stream>>>(gpart, pairs);
    k_loss   <<<1, 64, 0, stream>>>(pairs, out);
}

// Round 7
// 412.685 us; speedup vs baseline: 2.0092x; 1.3733x over previous
//
#include <hip/hip_runtime.h>
#include <hip/hip_fp16.h>

#define NN   100000
#define NE   1200000
#define MT   (NE + NN)      // edges + self loops
#define HH   4
#define HD   64             // H * OUT
#define NEG_SLOPE 0.2f
#define NB1  98             // ceil(NN/1024) scan blocks
#define NGB  25000          // gather blocks (NN/4)

static __device__ __forceinline__ unsigned short f2bf(float f) {
    unsigned int b = __float_as_uint(f);
    b += 0x7FFFu + ((b >> 16) & 1u);
    return (unsigned short)(b >> 16);
}

// fire-and-forget packed-f16 atomic add (no return): global_atomic_pk_add_f16
static __device__ __forceinline__ void pk_add_f16(__half* addr, unsigned val) {
    asm volatile("global_atomic_pk_add_f16 %0, %1, off"
                 :: "v"((unsigned long long)(uintptr_t)addr), "v"(val)
                 : "memory");
}

static __device__ __forceinline__ unsigned pack_h2(float a, float b) {
    return (unsigned)__half_as_ushort(__float2half(a)) |
           ((unsigned)__half_as_ushort(__float2half(b)) << 16);
}

// ---------------------------------------------------------------------------
// K1: fused col-histogram + content GEMM (x[:, :112] @ W, bf16 store) +
//     per-node scores: si -> f16 nd[n][0..3], sj -> f32. den slots nd[n][4..7]
//     stay zero (memset) for k_edge's pk-f16 atomics.
// ---------------------------------------------------------------------------
__global__ __launch_bounds__(256) void k_content(
    const float* __restrict__ x, const float* __restrict__ W,
    const float* __restrict__ att, const float* __restrict__ pos_att,
    const int* __restrict__ ei, int* __restrict__ cnt,
    unsigned short* __restrict__ contentb, __half* __restrict__ nd,
    float* __restrict__ sj)
{
    const int t = threadIdx.x;
    // fused histogram: fire-and-forget atomics drain under the GEMM
    for (int e = blockIdx.x * 256 + t; e < MT; e += gridDim.x * 256) {
        const int c = (e < NE) ? ei[NE + e] : (e - NE);
        atomicAdd(cnt + c, 1);
    }

    __shared__ float Wl[112 * 64];
    __shared__ float xsT[64 * 128];
    for (int i = t; i < 112 * 64; i += 256) Wl[i] = W[i];

    const int n0  = blockIdx.x * 128;
    const int oc  = (t & 7) * 8;
    const int h   = oc >> 4;
    const int ng4 = (t >> 3) * 4;

    float acc[4][8];
    #pragma unroll
    for (int j = 0; j < 4; ++j)
        #pragma unroll
        for (int o = 0; o < 8; ++o) acc[j][o] = 0.f;

    for (int ph = 0; ph < 2; ++ph) {
        __syncthreads();
        for (int idx = t; idx < 128 * 64; idx += 256) {
            const int nl = idx >> 6;
            const int kk = idx & 63;
            const int gn = n0 + nl;
            const float v = (gn < NN) ? x[gn * 128 + ph * 64 + kk] : 0.f;
            xsT[kk * 128 + (nl ^ ((kk & 31) << 2))] = v;
        }
        __syncthreads();
        const int klim = (ph == 0) ? 64 : 48;
        #pragma unroll 4
        for (int kk = 0; kk < klim; ++kk) {
            const int sw = (kk & 31) << 2;
            const float4 xv = *(const float4*)&xsT[kk * 128 + (ng4 ^ sw)];
            const int kg = ph * 64 + kk;
            const float4 w0 = *(const float4*)&Wl[kg * 64 + oc];
            const float4 w1 = *(const float4*)&Wl[kg * 64 + oc + 4];
            const float xa[4] = { xv.x, xv.y, xv.z, xv.w };
            #pragma unroll
            for (int j = 0; j < 4; ++j) {
                acc[j][0] = fmaf(xa[j], w0.x, acc[j][0]);
                acc[j][1] = fmaf(xa[j], w0.y, acc[j][1]);
                acc[j][2] = fmaf(xa[j], w0.z, acc[j][2]);
                acc[j][3] = fmaf(xa[j], w0.w, acc[j][3]);
                acc[j][4] = fmaf(xa[j], w1.x, acc[j][4]);
                acc[j][5] = fmaf(xa[j], w1.y, acc[j][5]);
                acc[j][6] = fmaf(xa[j], w1.z, acc[j][6]);
                acc[j][7] = fmaf(xa[j], w1.w, acc[j][7]);
            }
        }
    }

    const int dbase = oc & 15;
    float ati[8], atj[8], pti[8], ptj[8];
    #pragma unroll
    for (int j = 0; j < 8; ++j) {
        ati[j] = att[h * 32 + dbase + j];
        atj[j] = att[h * 32 + 16 + dbase + j];
        pti[j] = pos_att[h * 32 + dbase + j];
        ptj[j] = pos_att[h * 32 + 16 + dbase + j];
    }
    #pragma unroll
    for (int j = 0; j < 4; ++j) {
        const int gn = n0 + ng4 + j;
        float s1 = 0.f, s2 = 0.f;
        #pragma unroll
        for (int o = 0; o < 8; ++o) {
            s1 = fmaf(acc[j][o], ati[o], s1);
            s2 = fmaf(acc[j][o], atj[o], s2);
        }
        #pragma unroll
        for (int pp = 0; pp < 8; ++pp) {
            const int row = 48 + dbase + pp;
            const float pv = xsT[row * 128 + ((ng4 + j) ^ ((row & 31) << 2))];
            s1 = fmaf(pv, pti[pp], s1);
            s2 = fmaf(pv, ptj[pp], s2);
        }
        s1 += __shfl_xor(s1, 1);
        s2 += __shfl_xor(s2, 1);
        if (gn < NN) {
            if ((t & 1) == 0) nd[(size_t)gn * 8 + h] = __float2half(s1);
            else              sj[(size_t)gn * 4 + h] = s2;
            uint4 pk;
            pk.x = (unsigned)f2bf(acc[j][0]) | ((unsigned)f2bf(acc[j][1]) << 16);
            pk.y = (unsigned)f2bf(acc[j][2]) | ((unsigned)f2bf(acc[j][3]) << 16);
            pk.z = (unsigned)f2bf(acc[j][4]) | ((unsigned)f2bf(acc[j][5]) << 16);
            pk.w = (unsigned)f2bf(acc[j][6]) | ((unsigned)f2bf(acc[j][7]) << 16);
            *(uint4*)&contentb[(size_t)gn * 64 + oc] = pk;
        }
    }
}

// K2a: per-block exclusive scan of cnt (1024 elems/block)
__global__ __launch_bounds__(256) void k_scan1(
    const int* __restrict__ cnt, int* __restrict__ loc, int* __restrict__ bsum)
{
    const int b = blockIdx.x, t = threadIdx.x;
    const int base = b * 1024 + t * 4;
    int v[4], tsum = 0;
    #pragma unroll
    for (int j = 0; j < 4; ++j) {
        v[j] = (base + j < NN) ? cnt[base + j] : 0;
        tsum += v[j];
    }
    const int lane = t & 63, w = t >> 6;
    int sc = tsum;
    #pragma unroll
    for (int d = 1; d < 64; d <<= 1) {
        const int u = __shfl_up(sc, d);
        if (lane >= d) sc += u;
    }
    __shared__ int wsum[4];
    if (lane == 63) wsum[w] = sc;
    __syncthreads();
    int wbase = 0;
    for (int k = 0; k < w; ++k) wbase += wsum[k];
    int run = wbase + sc - tsum;
    #pragma unroll
    for (int j = 0; j < 4; ++j) {
        if (base + j < NN) loc[base + j] = run;
        run += v[j];
    }
    if (t == 255) bsum[b] = wbase + sc;
}

// K2b: add block bases (each block sums its own bsum prefix); emit offsets+woff
__global__ __launch_bounds__(256) void k_scan3(
    int* __restrict__ offsets, const int* __restrict__ bsum, int* __restrict__ woff)
{
    __shared__ int sb[NB1];
    for (int i = threadIdx.x; i < NB1; i += 256) sb[i] = bsum[i];
    __syncthreads();
    const int myblk = (blockIdx.x * 256) >> 10;   // constant within block
    int pre = 0;
    for (int k = 0; k < myblk; ++k) pre += sb[k];
    const int i = blockIdx.x * 256 + threadIdx.x;
    if (i == 0) offsets[NN] = MT;
    if (i >= NN) return;
    const int off = offsets[i] + pre;
    offsets[i] = off;
    woff[i] = off;
}

// ---------------------------------------------------------------------------
// K3: per edge: den via TWO pk-f16 atomics into nd[r][4..7]; 4B counting-sort
//     scatter of r by destination c.
// ---------------------------------------------------------------------------
__global__ __launch_bounds__(256) void k_edge(
    const int* __restrict__ ei, __half* __restrict__ nd,
    const float* __restrict__ sj, int* __restrict__ woff,
    int* __restrict__ sorted_r)
{
    const int e = blockIdx.x * 256 + threadIdx.x;
    if (e >= MT) return;
    int r, c;
    if (e < NE) { r = ei[e]; c = ei[NE + e]; } else { r = e - NE; c = r; }
    const uint2 sv = *(const uint2*)(nd + (size_t)r * 8);   // si4 as f16
    const float4 s2 = *(const float4*)(sj + (size_t)c * 4);
    float a[4];
    a[0] = __half2float(__ushort_as_half((unsigned short)(sv.x & 0xffff))) + s2.x;
    a[1] = __half2float(__ushort_as_half((unsigned short)(sv.x >> 16)))    + s2.y;
    a[2] = __half2float(__ushort_as_half((unsigned short)(sv.y & 0xffff))) + s2.z;
    a[3] = __half2float(__ushort_as_half((unsigned short)(sv.y >> 16)))    + s2.w;
    float ev[4];
    #pragma unroll
    for (int hh = 0; hh < 4; ++hh) {
        float v = a[hh];
        v = v > 0.f ? v : NEG_SLOPE * v;
        ev[hh] = __expf(v);
    }
    pk_add_f16(nd + (size_t)r * 8 + 4, pack_h2(ev[0], ev[1]));
    pk_add_f16(nd + (size_t)r * 8 + 6, pack_h2(ev[2], ev[3]));
    const int pos = atomicAdd(woff + c, 1);
    sorted_r[pos] = r;
}

// ---------------------------------------------------------------------------
// K4: one wave per destination node. Coalesced sorted_r preload + shfl
//     broadcast; per record ONE uint4 broadcast load of {si4,den4}, alpha
//     recomputed; bf16 content fma; batch-4 for MLP; per-block gram partials.
// ---------------------------------------------------------------------------
__global__ __launch_bounds__(256) void k_gather(
    const int* __restrict__ offsets, const int* __restrict__ sorted_r,
    const __half* __restrict__ nd, const float* __restrict__ sj,
    const unsigned short* __restrict__ contentb, const float* __restrict__ bias,
    float* __restrict__ out, float* __restrict__ gpart)
{
    const int lane = threadIdx.x & 63;
    const int wid  = threadIdx.x >> 6;
    const int n    = blockIdx.x * 4 + wid;
    const int h    = lane >> 4;
    const int s0 = offsets[n], s1 = offsets[n + 1];
    const float sjh = sj[(size_t)n * 4 + h];
    float acc = 0.f;
    float a0=0,a1=0,a2=0,a3=0,a4=0,a5=0,a6=0,a7=0,a8=0,a9=0;

    for (int base = s0; base < s1; base += 64) {
        const int cd = min(64, s1 - base);
        const int rl = (lane < cd) ? sorted_r[base + lane] : 0;
        int j = 0;
        for (; j + 3 < cd; j += 4) {
            int rk[4];
            uint4 nr[4];
            float cv[4];
            #pragma unroll
            for (int k = 0; k < 4; ++k) rk[k] = __shfl(rl, j + k);
            #pragma unroll
            for (int k = 0; k < 4; ++k) nr[k] = *(const uint4*)(nd + (size_t)rk[k] * 8);
            #pragma unroll
            for (int k = 0; k < 4; ++k)
                cv[k] = __uint_as_float((unsigned)contentb[(size_t)rk[k] * 64 + lane] << 16);
            #pragma unroll
            for (int k = 0; k < 4; ++k) {
                const unsigned sw = (h & 2) ? nr[k].y : nr[k].x;
                const unsigned dw = (h & 2) ? nr[k].w : nr[k].z;
                const unsigned short sb = (h & 1) ? (unsigned short)(sw >> 16) : (unsigned short)(sw & 0xffff);
                const unsigned short db = (h & 1) ? (unsigned short)(dw >> 16) : (unsigned short)(dw & 0xffff);
                float v = __half2float(__ushort_as_half(sb)) + sjh;
                v = v > 0.f ? v : NEG_SLOPE * v;
                const float al = __expf(v) / (__half2float(__ushort_as_half(db)) + 1e-10f);
                acc = fmaf(cv[k], al, acc);
                const float b0 = __shfl(al, 0);
                const float b1 = __shfl(al, 16);
                const float b2 = __shfl(al, 32);
                const float b3 = __shfl(al, 48);
                a0=fmaf(b0,b0,a0); a1=fmaf(b0,b1,a1); a2=fmaf(b0,b2,a2); a3=fmaf(b0,b3,a3);
                a4=fmaf(b1,b1,a4); a5=fmaf(b1,b2,a5); a6=fmaf(b1,b3,a6);
                a7=fmaf(b2,b2,a7); a8=fmaf(b2,b3,a8); a9=fmaf(b3,b3,a9);
            }
        }
        for (; j < cd; ++j) {
            const int rk = __shfl(rl, j);
            const uint4 nr = *(const uint4*)(nd + (size_t)rk * 8);
            const unsigned sw = (h & 2) ? nr.y : nr.x;
            const unsigned dw = (h & 2) ? nr.w : nr.z;
            const unsigned short sb = (h & 1) ? (unsigned short)(sw >> 16) : (unsigned short)(sw & 0xffff);
            const unsigned short db = (h & 1) ? (unsigned short)(dw >> 16) : (unsigned short)(dw & 0xffff);
            float v = __half2float(__ushort_as_half(sb)) + sjh;
            v = v > 0.f ? v : NEG_SLOPE * v;
            const float al = __expf(v) / (__half2float(__ushort_as_half(db)) + 1e-10f);
            const float cvv = __uint_as_float((unsigned)contentb[(size_t)rk * 64 + lane] << 16);
            acc = fmaf(cvv, al, acc);
            const float b0 = __shfl(al, 0);
            const float b1 = __shfl(al, 16);
            const float b2 = __shfl(al, 32);
            const float b3 = __shfl(al, 48);
            a0=fmaf(b0,b0,a0); a1=fmaf(b0,b1,a1); a2=fmaf(b0,b2,a2); a3=fmaf(b0,b3,a3);
            a4=fmaf(b1,b1,a4); a5=fmaf(b1,b2,a5); a6=fmaf(b1,b3,a6);
            a7=fmaf(b2,b2,a7); a8=fmaf(b2,b3,a8); a9=fmaf(b3,b3,a9);
        }
    }
    out[(size_t)n * 64 + lane] = acc + bias[lane];

    __shared__ float red[4][10];
    if (lane == 0) {
        red[wid][0]=a0; red[wid][1]=a1; red[wid][2]=a2; red[wid][3]=a3; red[wid][4]=a4;
        red[wid][5]=a5; red[wid][6]=a6; red[wid][7]=a7; red[wid][8]=a8; red[wid][9]=a9;
    }
    __syncthreads();
    if (threadIdx.x < 10) {
        gpart[(size_t)blockIdx.x * 10 + threadIdx.x] =
            red[0][threadIdx.x] + red[1][threadIdx.x] +
            red[2][threadIdx.x] + red[3][threadIdx.x];
    }
}

// K5: reduce per-block gram partials -> pairs (f64)
__global__ __launch_bounds__(256) void k_gred(
    const float* __restrict__ gpart, double* __restrict__ pairs)
{
    const int row = blockIdx.x * 256 + threadIdx.x;
    float v[10];
    #pragma unroll
    for (int i = 0; i < 10; ++i)
        v[i] = (row < NGB) ? gpart[(size_t)row * 10 + i] : 0.f;
    #pragma unroll
    for (int m = 32; m >= 1; m >>= 1)
        #pragma unroll
        for (int i = 0; i < 10; ++i) v[i] += __shfl_xor(v[i], m);
    __shared__ float red[4][10];
    const int lane = threadIdx.x & 63, wid = threadIdx.x >> 6;
    if (lane == 0)
        #pragma unroll
        for (int i = 0; i < 10; ++i) red[wid][i] = v[i];
    __syncthreads();
    if (threadIdx.x < 10) {
        const double s = (double)red[0][threadIdx.x] + red[1][threadIdx.x]
                       + red[2][threadIdx.x] + red[3][threadIdx.x];
        atomicAdd(pairs + threadIdx.x, s);
    }
}

// K6: finalize diversity loss
__global__ void k_loss(const double* __restrict__ ps, float* __restrict__ out)
{
    if (threadIdx.x == 0 && blockIdx.x == 0) {
        const double s00=ps[0], s01=ps[1], s02=ps[2], s03=ps[3], s11=ps[4];
        const double s12=ps[5], s13=ps[6], s22=ps[7], s23=ps[8], s33=ps[9];
        const double n0 = fmax(sqrt(s00), 1e-12);
        const double n1 = fmax(sqrt(s11), 1e-12);
        const double n2 = fmax(sqrt(s22), 1e-12);
        const double n3 = fmax(sqrt(s33), 1e-12);
        double loss = 2.0 * ( s01/(n0*n1) + s02/(n0*n2) + s03/(n0*n3)
                            + s12/(n1*n2) + s13/(n1*n3) + s23/(n2*n3) );
        loss = loss / 16.0 * 0.1;
        out[NN * HD] = (float)loss;
    }
}

extern "C" void kernel_launch(void* const* d_in, const int* in_sizes, int n_in,
                              void* d_out, int out_size, void* d_ws, size_t ws_size,
                              hipStream_t stream)
{
    const float* x       = (const float*)d_in[0];
    const int*   ei      = (const int*)d_in[1];
    const float* W       = (const float*)d_in[2];
    const float* att     = (const float*)d_in[3];
    const float* pos_att = (const float*)d_in[4];
    const float* bias    = (const float*)d_in[5];
    float* out = (float*)d_out;

    // workspace layout (16B aligned). memset region = pairs|nd|cnt contiguous.
    char* p = (char*)d_ws;
    double* pairs    = (double*)p;         p += 128;
    __half* nd       = (__half*)p;         p += (size_t)NN * 8 * 2;     // si4+den4 f16: 1.6 MB
    int*    cnt      = (int*)p;            p += (size_t)NN * 4;         // 400 KB (becomes woff)
    int*    offsets  = (int*)p;            p += (size_t)(NN + 4) * 4;   // 400 KB
    int*    bsum     = (int*)p;            p += 512;
    int*    sorted_r = (int*)p;            p += (size_t)MT * 4;         // 5.2 MB
    float*  sj       = (float*)p;          p += (size_t)NN * 4 * 4;     // 1.6 MB
    float*  gpart    = (float*)p;          p += (size_t)NGB * 10 * 4;   // 1.0 MB
    unsigned short* contentb = (unsigned short*)p; p += (size_t)NN * 64 * 2; // 12.8 MB

    (void)hipMemsetAsync(pairs, 0, 128 + (size_t)NN * 16 + (size_t)NN * 4, stream);

    k_content<<<(NN + 127) / 128, 256, 0, stream>>>(x, W, att, pos_att, ei, cnt,
                                                    contentb, nd, sj);
    k_scan1  <<<NB1, 256, 0, stream>>>(cnt, offsets, bsum);
    k_scan3  <<<(NN + 255) / 256, 256, 0, stream>>>(offsets, bsum, cnt);
    k_edge   <<<(MT + 255) / 256, 256, 0, stream>>>(ei, nd, sj, cnt, sorted_r);
    k_gather <<<NGB, 256, 0, stream>>>(offsets, sorted_r, nd, sj, contentb, bias, out, gpart);
    k_gred   <<<(NGB + 255) / 256, 256, 0, stream>>>(gpart, pairs);
    k_loss   <<<1, 64, 0, stream>>>(pairs, out);
}